// Round 1
// baseline (1245.472 us; speedup 1.0000x reference)
//
#include <hip/hip_runtime.h>

#define BATCH 128
#define DIM 128
#define KP1 4097
#define NOUT 200000
#define MEM_N (NOUT * DIM)   // 25,600,000 floats per bank

// ---------------------------------------------------------------------------
// Momentum update of the 128 selected rows (after banks are copied to d_out).
// pos = mem[y]*0.5 + feat*0.5 ; out[y] = pos / ||pos||.
// Reads ORIGINAL memory (matches reference: gather+update both use pristine
// banks). Last-wins on duplicate y to match scatter .set semantics.
// ---------------------------------------------------------------------------
__global__ void momentum_rows(const float* __restrict__ l,
                              const float* __restrict__ ab,
                              const float* __restrict__ ori,
                              const int*   __restrict__ y,
                              const float* __restrict__ ml,
                              const float* __restrict__ mab,
                              const float* __restrict__ mo,
                              float* __restrict__ out_l,
                              float* __restrict__ out_ab,
                              float* __restrict__ out_o) {
    const int b  = blockIdx.x;
    const int yb = y[b];
    // last-wins: if a later batch element targets the same row, this block is dead
    for (int b2 = b + 1; b2 < BATCH; ++b2)
        if (y[b2] == yb) return;

    const int t = threadIdx.x;                 // 128 threads = 2 waves
    const size_t mbase = (size_t)yb * DIM + t;
    const int    fbase = b * DIM + t;

    float p0 = ml [mbase] * 0.5f + l  [fbase] * 0.5f;
    float p1 = mab[mbase] * 0.5f + ab [fbase] * 0.5f;
    float p2 = mo [mbase] * 0.5f + ori[fbase] * 0.5f;

    float s0 = p0 * p0, s1 = p1 * p1, s2 = p2 * p2;
#pragma unroll
    for (int off = 32; off > 0; off >>= 1) {
        s0 += __shfl_down(s0, off, 64);
        s1 += __shfl_down(s1, off, 64);
        s2 += __shfl_down(s2, off, 64);
    }
    __shared__ float red[3][2];
    if ((t & 63) == 0) { red[0][t >> 6] = s0; red[1][t >> 6] = s1; red[2][t >> 6] = s2; }
    __syncthreads();
    const float i0 = 1.0f / sqrtf(red[0][0] + red[0][1]);
    const float i1 = 1.0f / sqrtf(red[1][0] + red[1][1]);
    const float i2 = 1.0f / sqrtf(red[2][0] + red[2][1]);

    out_l [mbase] = p0 * i0;
    out_ab[mbase] = p1 * i1;
    out_o [mbase] = p2 * i2;
}

// ---------------------------------------------------------------------------
// Scores: thread = one (b,k). Gathers 3 rows of 512B (float4 stream per row),
// dots against LDS-staged features (same-address LDS reads = broadcast, no
// bank conflicts). Output writes coalesced (thread->k contiguous).
//   outs[0] = w_l  . ab    outs[1] = w_ab . l     outs[2] = w_l  . ori
//   outs[3] = w_ori. l     outs[4] = w_ori. ab    outs[5] = w_ab . ori
// ---------------------------------------------------------------------------
__global__ void scores_kernel(const float* __restrict__ l,
                              const float* __restrict__ ab,
                              const float* __restrict__ ori,
                              const int*   __restrict__ idx,
                              const float* __restrict__ ml,
                              const float* __restrict__ mab,
                              const float* __restrict__ mo,
                              float* __restrict__ out) {
    __shared__ float4 sl[DIM / 4], sab[DIM / 4], sori[DIM / 4];
    const int b = blockIdx.y;
    const int t = threadIdx.x;
    if (t < DIM / 4) {
        sl  [t] = ((const float4*)(l   + b * DIM))[t];
        sab [t] = ((const float4*)(ab  + b * DIM))[t];
        sori[t] = ((const float4*)(ori + b * DIM))[t];
    }
    __syncthreads();

    const int k = blockIdx.x * blockDim.x + t;
    if (k >= KP1) return;
    const int row = idx[b * KP1 + k];

    const float4* rl  = (const float4*)(ml  + (size_t)row * DIM);
    const float4* rab = (const float4*)(mab + (size_t)row * DIM);
    const float4* ro  = (const float4*)(mo  + (size_t)row * DIM);

    float a0 = 0.f, a1 = 0.f, a2 = 0.f, a3 = 0.f, a4 = 0.f, a5 = 0.f;

    // bank-sequential row streams: at most 64 live cache lines per wave per bank
    for (int d = 0; d < DIM / 4; ++d) {
        float4 w = rl[d], f1 = sab[d], f2 = sori[d];
        a0 += w.x * f1.x + w.y * f1.y + w.z * f1.z + w.w * f1.w;
        a2 += w.x * f2.x + w.y * f2.y + w.z * f2.z + w.w * f2.w;
    }
    for (int d = 0; d < DIM / 4; ++d) {
        float4 w = rab[d], f1 = sl[d], f2 = sori[d];
        a1 += w.x * f1.x + w.y * f1.y + w.z * f1.z + w.w * f1.w;
        a5 += w.x * f2.x + w.y * f2.y + w.z * f2.z + w.w * f2.w;
    }
    for (int d = 0; d < DIM / 4; ++d) {
        float4 w = ro[d], f1 = sl[d], f2 = sab[d];
        a3 += w.x * f1.x + w.y * f1.y + w.z * f1.z + w.w * f1.w;
        a4 += w.x * f2.x + w.y * f2.y + w.z * f2.z + w.w * f2.w;
    }

    const size_t plane = (size_t)BATCH * KP1;
    const size_t base  = (size_t)b * KP1 + k;
    out[base]             = a0;
    out[plane + base]     = a1;
    out[2 * plane + base] = a2;
    out[3 * plane + base] = a3;
    out[4 * plane + base] = a4;
    out[5 * plane + base] = a5;
}

extern "C" void kernel_launch(void* const* d_in, const int* in_sizes, int n_in,
                              void* d_out, int out_size, void* d_ws, size_t ws_size,
                              hipStream_t stream) {
    const float* l   = (const float*)d_in[0];
    const float* ab  = (const float*)d_in[1];
    const float* ori = (const float*)d_in[2];
    const int*   y   = (const int*)d_in[3];
    const int*   idx = (const int*)d_in[4];
    const float* ml  = (const float*)d_in[5];
    const float* mab = (const float*)d_in[6];
    const float* mo  = (const float*)d_in[7];

    float* out        = (float*)d_out;
    float* out_scores = out;
    float* out_l  = out + (size_t)6 * BATCH * KP1;   // 3,146,496
    float* out_ab = out_l  + (size_t)MEM_N;
    float* out_o  = out_ab + (size_t)MEM_N;

    // 1) scores (reads only pristine inputs)
    dim3 sgrid((KP1 + 255) / 256, BATCH);
    scores_kernel<<<sgrid, 256, 0, stream>>>(l, ab, ori, idx, ml, mab, mo, out_scores);

    // 2) bank pass-through via copy engines
    const size_t bank_bytes = (size_t)MEM_N * sizeof(float);
    hipMemcpyAsync(out_l,  ml,  bank_bytes, hipMemcpyDeviceToDevice, stream);
    hipMemcpyAsync(out_ab, mab, bank_bytes, hipMemcpyDeviceToDevice, stream);
    hipMemcpyAsync(out_o,  mo,  bank_bytes, hipMemcpyDeviceToDevice, stream);

    // 3) overwrite the 128 updated rows (after the copies)
    momentum_rows<<<BATCH, DIM, 0, stream>>>(l, ab, ori, y, ml, mab, mo,
                                             out_l, out_ab, out_o);
}